// Round 7
// baseline (173.115 us; speedup 1.0000x reference)
//
#include <hip/hip_runtime.h>

// Corr2Cost = pure shear permutation (single-tap is EXACT: linspace(-m,m,2m+1)
// step is exactly 1.0 -> w1 == 0): out[bc,k,h,w] = in[bc, base+k-m, h, w],
// base = ux ? w : h, zero outside [0,D). Validated exact in R4/R5 (passed).
//
// R6 theory (resubmitted after broker timeout): R1-R5 all sat at 2.1-2.3 TB/s
// regardless of occupancy/pipelining -> wall is DRAM run-length (256-512B
// runs at 12-48KB strides), not latency. Fix: tile by (bc, h-triple). Read
// in[bc,d,h0:h0+3,:] = 1.5KB contiguous per d; shear-scatter into 151.5KB
// dynamic-LDS tile [K][3][W] (lane-group rotation -> bank-conflict-free);
// stream out[bc,k,h0:h0+3,:] = 1.5KB contiguous per k. XCD-chunk swizzle
// makes the 32 co-resident h-tiles of one bc reconstruct sequential sweeps.

#define B_ 8
#define C_ 2
#define D_ 128
#define H_ 96
#define W_ 128
#define TH 3
#define NT 1024
#define NHT (H_ / TH)          // 32 h-tiles
#define NBLK (B_ * C_ * NHT)   // 512 blocks = 2 rounds of 256 CUs

extern __shared__ float lds[]; // [K][TH][W_]

__global__ __launch_bounds__(NT) void corr2cost_kernel(
    const float* __restrict__ corr,
    const int* __restrict__ mp,
    const int* __restrict__ up,
    float* __restrict__ out,
    const int K) {
  // bijective XCD-chunk swizzle (NBLK % 8 == 0): XCD x runs logical blocks
  // [x*64, (x+1)*64) = all h-tiles of 2 consecutive bc's, concurrently.
  const int raw = blockIdx.x;
  const int bid = (raw & 7) * (NBLK / 8) + (raw >> 3);
  const int ht  = bid & (NHT - 1);
  const int bc  = bid >> 5;            // NHT == 32
  const int h0  = ht * TH;

  const int t  = threadIdx.x;
  const int m  = *mp;
  const int ux = *up;
  const int HW = H_ * W_;

  // ---- phase 1: read all d-rows (1.5KB contiguous runs), shear-scatter ----
  // Bank math (ux=1): dword addr = (k*TH+hh)*128 + w with 384*k and 128*hh
  // both = 0 (mod 32) -> bank = w & 31. Each 32-lane group covers 8 w4
  // groups; rotation j' = (s + (l>>3))&3 spreads step s across all 32 banks
  // -> exactly 2 lanes/bank for wave64 = free (m136).
  const int rot = (t >> 3) & 3;
  const float* __restrict__ src =
      corr + (size_t)bc * D_ * HW + (size_t)h0 * W_;
#pragma unroll
  for (int p = 0; p < D_ * TH * (W_ / 4) / NT; ++p) {  // 12 exact passes
    const int i  = t + p * NT;
    const int d  = i / (TH * W_ / 4);        // i / 96
    const int r  = i - d * (TH * W_ / 4);
    const int hh = r >> 5;                   // 0..TH-1
    const int w4 = (r & 31) * 4;
    const float4 v =
        *reinterpret_cast<const float4*>(src + (size_t)d * HW + hh * W_ + w4);
    const float vv[4] = {v.x, v.y, v.z, v.w};
#pragma unroll
    for (int s = 0; s < 4; ++s) {
      const int j = (s + rot) & 3;
      const int w = w4 + j;
      const int k = d + m - (ux ? w : (h0 + hh));
      if ((unsigned)k < (unsigned)K)         // each input elem -> <=1 output
        lds[(k * TH + hh) * W_ + w] = vv[j];
    }
  }
  __syncthreads();

  // ---- phase 2: stream out[k][h0:h0+3][:] (1.5KB contiguous runs per k) ----
  // OOB (k,w)/(k,h) corners were never written in LDS -> masked to 0 here.
  float* __restrict__ dst = out + (size_t)bc * K * HW + (size_t)h0 * W_;
  const int nf4 = K * TH * (W_ / 4);         // 9696 float4
  for (int i = t; i < nf4; i += NT) {
    const int k  = i / (TH * W_ / 4);
    const int r  = i - k * (TH * W_ / 4);
    const int hh = r >> 5;
    const int w4 = (r & 31) * 4;
    const float4 lv =
        *reinterpret_cast<const float4*>(&lds[(k * TH + hh) * W_ + w4]);
    float o[4] = {lv.x, lv.y, lv.z, lv.w};
#pragma unroll
    for (int j = 0; j < 4; ++j) {
      const int d = (ux ? (w4 + j) : (h0 + hh)) + k - m;
      if ((unsigned)d >= (unsigned)D_) o[j] = 0.0f;   // zero-pad mask
    }
    *reinterpret_cast<float4*>(dst + (size_t)k * HW + hh * W_ + w4) =
        make_float4(o[0], o[1], o[2], o[3]);
  }
}

extern "C" void kernel_launch(void* const* d_in, const int* in_sizes, int n_in,
                              void* d_out, int out_size, void* d_ws, size_t ws_size,
                              hipStream_t stream) {
  const float* corr    = (const float*)d_in[0];
  const int*   maxdisp = (const int*)d_in[1];
  const int*   is_ux   = (const int*)d_in[2];
  float*       out     = (float*)d_out;

  const int K = out_size / (B_ * C_ * H_ * W_);      // 101 (host-derivable)
  const int ldsbytes = K * TH * W_ * 4;              // 155136 <= 163840
  // Idempotent host-side attribute set (not a stream op -> graph-capture
  // safe; m201 precedent for >64KB dynamic LDS on gfx950).
  hipFuncSetAttribute((const void*)corr2cost_kernel,
                      hipFuncAttributeMaxDynamicSharedMemorySize, ldsbytes);
  corr2cost_kernel<<<NBLK, NT, ldsbytes, stream>>>(corr, maxdisp, is_ux, out, K);
}